// Round 3
// baseline (136.221 us; speedup 1.0000x reference)
//
#include <hip/hip_runtime.h>
#include <hip/hip_bf16.h>

#define NN 8192
#define INF_ 256
#define OUTF 64
#define ALPHA 0.2f
#define LOG2E 1.44269504088896f

typedef __attribute__((ext_vector_type(8))) short short8;
typedef __attribute__((ext_vector_type(4))) float f32x4;

static __device__ __forceinline__ unsigned short f2bf(float f) {
  unsigned u = __builtin_bit_cast(unsigned, f);
  u += 0x7fffu + ((u >> 16) & 1u);          // RNE; inputs are finite
  return (unsigned short)(u >> 16);
}

static __device__ __forceinline__ float pvalm(unsigned bit, float s2v, float s1v, float msc) {
  const float x = s1v + s2v;
  const float lr = fmaxf(x, ALPHA * x);      // leaky_relu, alpha<1
  const float e = exp2f(fmaf(lr, LOG2E, -msc));
  return bit ? e : 0.f;
}

static __device__ __forceinline__ ushort4 p4m(unsigned mb, const float4 s,
                                              float s1v, float msc, float& lp) {
  const float p0 = pvalm(mb & 1u, s.x, s1v, msc);
  const float p1 = pvalm(mb & 2u, s.y, s1v, msc);
  const float p2 = pvalm(mb & 4u, s.z, s1v, msc);
  const float p3 = pvalm(mb & 8u, s.w, s1v, msc);
  lp += (p0 + p1) + (p2 + p3);
  ushort4 r;
  r.x = f2bf(p0); r.y = f2bf(p1); r.z = f2bf(p2); r.w = f2bf(p3);
  return r;
}

static __device__ __forceinline__ float pvali(int a, float s2v, float s1v, float msc) {
  const float x = s1v + s2v;
  const float lr = fmaxf(x, ALPHA * x);
  const float e = exp2f(fmaf(lr, LOG2E, -msc));
  return a > 0 ? e : 0.f;
}

static __device__ __forceinline__ ushort4 p4i(const int4 a, const float4 s,
                                              float s1v, float msc, float& lp) {
  const float p0 = pvali(a.x, s.x, s1v, msc);
  const float p1 = pvali(a.y, s.y, s1v, msc);
  const float p2 = pvali(a.z, s.z, s1v, msc);
  const float p3 = pvali(a.w, s.w, s1v, msc);
  lp += (p0 + p1) + (p2 + p3);
  ushort4 r;
  r.x = f2bf(p0); r.y = f2bf(p1); r.z = f2bf(p2); r.w = f2bf(p3);
  return r;
}

// ---------------- Kernel P: adj int32 -> 1-bit mask via ballot (pure stream, 32x compress)
// Wave processes 2048 contiguous elements: 32 coalesced dword loads + 32 ballots.
__global__ __launch_bounds__(256) void k_pack(const int* __restrict__ adj,
                                              unsigned long long* __restrict__ mask) {
  const int lane = threadIdx.x & 63;
  const int gw = (blockIdx.x << 2) + (threadIdx.x >> 6);   // global wave id
  const int* p = adj + (size_t)gw * 2048 + lane;
  unsigned long long my = 0ull;
  #pragma unroll
  for (int q = 0; q < 32; ++q) {
    const int v = p[q * 64];
    const unsigned long long b = __ballot(v > 0);   // bit i = lane i's element
    if (lane == q) my = b;
  }
  if (lane < 32) mask[(size_t)gw * 32 + lane] = my;
}

// ---------------- Kernel A: h' = X@W  ->  hp_t (bf16, transposed), s1, s2, per-block s2max
__global__ __launch_bounds__(256) void k_prep(
    const float* __restrict__ X, const float* __restrict__ W,
    const float* __restrict__ a1, const float* __restrict__ a2,
    unsigned short* __restrict__ hpt, float* __restrict__ s1,
    float* __restrict__ s2, float* __restrict__ pmax)
{
  __shared__ float Ws[INF_ * OUTF];   // 64 KB
  __shared__ float Xs[32 * INF_];     // 32 KB
  __shared__ float sm8[8];
  const int t = threadIdx.x;
  const int ib = blockIdx.x;

  #pragma unroll
  for (int i = 0; i < 16; ++i) {
    const int idx = (i * 256 + t) * 4;
    *reinterpret_cast<float4*>(&Ws[idx]) = *reinterpret_cast<const float4*>(&W[idx]);
  }
  const float* Xb = X + (size_t)ib * 32 * INF_;
  #pragma unroll
  for (int i = 0; i < 8; ++i) {
    const int idx = (i * 256 + t) * 4;
    *reinterpret_cast<float4*>(&Xs[idx]) = *reinterpret_cast<const float4*>(&Xb[idx]);
  }
  __syncthreads();

  const int rg = t >> 5;          // 0..7 -> rows 4*rg..4*rg+3
  const int r0 = rg * 4;
  const int c0 = 2 * (t & 31);    // 2 consecutive output features
  float acc[4][2] = {{0.f,0.f},{0.f,0.f},{0.f,0.f},{0.f,0.f}};

  for (int k = 0; k < INF_; k += 4) {
    float xv[4][4];
    #pragma unroll
    for (int rr = 0; rr < 4; ++rr)
      *reinterpret_cast<float4*>(&xv[rr][0]) =
          *reinterpret_cast<const float4*>(&Xs[(r0 + rr) * INF_ + k]);
    #pragma unroll
    for (int kk = 0; kk < 4; ++kk) {
      const float2 wv = *reinterpret_cast<const float2*>(&Ws[(k + kk) * OUTF + c0]);
      #pragma unroll
      for (int rr = 0; rr < 4; ++rr) {
        acc[rr][0] = fmaf(xv[rr][kk], wv.x, acc[rr][0]);
        acc[rr][1] = fmaf(xv[rr][kk], wv.y, acc[rr][1]);
      }
    }
  }

  const float a10 = a1[c0], a11 = a1[c0 + 1];
  const float a20 = a2[c0], a21 = a2[c0 + 1];
  float sp1[4], sp2[4];
  #pragma unroll
  for (int rr = 0; rr < 4; ++rr) {
    sp1[rr] = acc[rr][0] * a10 + acc[rr][1] * a11;
    sp2[rr] = acc[rr][0] * a20 + acc[rr][1] * a21;
  }
  #pragma unroll
  for (int d = 1; d < 32; d <<= 1) {
    #pragma unroll
    for (int rr = 0; rr < 4; ++rr) {
      sp1[rr] += __shfl_xor(sp1[rr], d, 64);
      sp2[rr] += __shfl_xor(sp2[rr], d, 64);
    }
  }

  const int gr = ib * 32 + r0;
  #pragma unroll
  for (int cc = 0; cc < 2; ++cc) {
    ushort4 pk;
    pk.x = f2bf(acc[0][cc]); pk.y = f2bf(acc[1][cc]);
    pk.z = f2bf(acc[2][cc]); pk.w = f2bf(acc[3][cc]);
    *reinterpret_cast<ushort4*>(&hpt[(size_t)(c0 + cc) * NN + gr]) = pk;
  }
  if ((t & 31) == 0) {
    #pragma unroll
    for (int rr = 0; rr < 4; ++rr) { s1[gr + rr] = sp1[rr]; s2[gr + rr] = sp2[rr]; }
    sm8[rg] = fmaxf(fmaxf(sp2[0], sp2[1]), fmaxf(sp2[2], sp2[3]));
  }
  __syncthreads();
  if (t == 0) {
    float m = sm8[0];
    #pragma unroll
    for (int i = 1; i < 8; ++i) m = fmaxf(m, sm8[i]);
    pmax[ib] = m;
  }
}

// ---------------- Kernel R (fallback path only): global max of s2
__global__ void k_rmax(const float* __restrict__ pmax, float* __restrict__ s2max) {
  const int t = threadIdx.x;  // 64 threads
  float m = fmaxf(fmaxf(pmax[t], pmax[t + 64]), fmaxf(pmax[t + 128], pmax[t + 192]));
  #pragma unroll
  for (int d = 1; d < 64; d <<= 1) m = fmaxf(m, __shfl_xor(m, d, 64));
  if (t == 0) *s2max = m;
}

// ---------------- Kernel C: fused masked-softmax + attn@h' + elu, reading 1-bit mask.
// 512 blocks x 512 thr. Block owns 16 output rows. 8 waves split K 8-ways (1024 each).
// All loop inputs (mask 8MB, hpt 1MB, s2 32KB) are L2-resident -> latency hideable.
__global__ __launch_bounds__(512, 4) void k_main_mask(
    const unsigned int* __restrict__ mask, const unsigned short* __restrict__ hpt,
    const float* __restrict__ s1g, const float* __restrict__ s2g,
    const float* __restrict__ pmax, float* __restrict__ out)
{
  __shared__ float red[8][64][17];   // +1 pad: conflict-free
  __shared__ float lden[8][16];
  const int t = threadIdx.x;
  const int lane = t & 63;
  const int w = t >> 6;            // K-chunk id 0..7
  const int rb = blockIdx.x;       // row-tile
  const int r15 = lane & 15;       // A-fragment row within tile
  const int kq = lane >> 4;        // k-quad 0..3 (8 cols each)
  const int row = rb * 16 + r15;

  // inline global s2-max reduction (replaces k_rmax)
  float mm = fmaxf(fmaxf(pmax[lane], pmax[lane + 64]),
                   fmaxf(pmax[lane + 128], pmax[lane + 192]));
  #pragma unroll
  for (int d = 1; d < 64; d <<= 1) mm = fmaxf(mm, __shfl_xor(mm, d, 64));
  const float SM = mm;

  const float s1v = s1g[row];
  const float xm = s1v + SM;
  const float msc = fmaxf(xm, ALPHA * xm) * LOG2E;  // M_i*log2e >= row max (lrelu monotone)

  const unsigned int* mP = mask + (size_t)row * (NN / 32) + w * 32;  // u32 per 32 cols
  const float* sP = s2g + w * 1024 + kq * 8;
  const unsigned short* bP = hpt + (size_t)r15 * NN + w * 1024 + kq * 8;
  const int sh = kq * 8;

  f32x4 acc0 = {0.f,0.f,0.f,0.f}, acc1 = acc0, acc2 = acc0, acc3 = acc0;
  float lpart = 0.f;

  // prefetch k-step 0
  unsigned mw = mP[0];
  float4 sA = *reinterpret_cast<const float4*>(sP);
  float4 sB = *reinterpret_cast<const float4*>(sP + 4);
  short8 b0 = *reinterpret_cast<const short8*>(bP);
  short8 b1 = *reinterpret_cast<const short8*>(bP + 16 * NN);
  short8 b2 = *reinterpret_cast<const short8*>(bP + 32 * NN);
  short8 b3 = *reinterpret_cast<const short8*>(bP + 48 * NN);

  for (int st = 0; st < 32; ++st) {
    const int ns = (st < 31) ? st + 1 : 0;          // tail reloads step0 (discarded)
    const int nk = ns * 32;
    const unsigned nmw = mP[ns];
    const float4 nsA = *reinterpret_cast<const float4*>(sP + nk);
    const float4 nsB = *reinterpret_cast<const float4*>(sP + nk + 4);
    const short8 nb0 = *reinterpret_cast<const short8*>(bP + nk);
    const short8 nb1 = *reinterpret_cast<const short8*>(bP + nk + 16 * NN);
    const short8 nb2 = *reinterpret_cast<const short8*>(bP + nk + 32 * NN);
    const short8 nb3 = *reinterpret_cast<const short8*>(bP + nk + 48 * NN);

    const unsigned mb = mw >> sh;
    const ushort4 lo = p4m(mb, sA, s1v, msc, lpart);
    const ushort4 hi = p4m(mb >> 4, sB, s1v, msc, lpart);
    short8 af;
    af[0] = (short)lo.x; af[1] = (short)lo.y; af[2] = (short)lo.z; af[3] = (short)lo.w;
    af[4] = (short)hi.x; af[5] = (short)hi.y; af[6] = (short)hi.z; af[7] = (short)hi.w;
    acc0 = __builtin_amdgcn_mfma_f32_16x16x32_bf16(af, b0, acc0, 0, 0, 0);
    acc1 = __builtin_amdgcn_mfma_f32_16x16x32_bf16(af, b1, acc1, 0, 0, 0);
    acc2 = __builtin_amdgcn_mfma_f32_16x16x32_bf16(af, b2, acc2, 0, 0, 0);
    acc3 = __builtin_amdgcn_mfma_f32_16x16x32_bf16(af, b3, acc3, 0, 0, 0);

    mw = nmw; sA = nsA; sB = nsB;
    b0 = nb0; b1 = nb1; b2 = nb2; b3 = nb3;
  }

  lpart += __shfl_xor(lpart, 16, 64);
  lpart += __shfl_xor(lpart, 32, 64);
  if (kq == 0) lden[w][r15] = lpart;

  #pragma unroll
  for (int r = 0; r < 4; ++r) {
    red[w][lane][r]      = acc0[r];
    red[w][lane][4 + r]  = acc1[r];
    red[w][lane][8 + r]  = acc2[r];
    red[w][lane][12 + r] = acc3[r];
  }
  __syncthreads();

  const int orow = t >> 5;     // 0..15
  const int oc = t & 31;       // cols oc and oc+32
  float den = 0.f;
  #pragma unroll
  for (int ww = 0; ww < 8; ++ww) den += lden[ww][orow];
  const float inv = 1.f / den;
  #pragma unroll
  for (int half = 0; half < 2; ++half) {
    const int col = oc + 32 * half;
    const int s = col >> 4, c = col & 15;
    const int li = (orow >> 2) * 16 + c;
    const int ri = s * 4 + (orow & 3);
    float v = 0.f;
    #pragma unroll
    for (int ww = 0; ww < 8; ++ww) v += red[ww][li][ri];
    const float dv = v * inv;
    out[(size_t)(rb * 16 + orow) * OUTF + col] = dv > 0.f ? dv : (expf(dv) - 1.f);
  }
}

// ---------------- Fallback (small ws): R2's direct-adj main kernel
__global__ __launch_bounds__(512, 4) void k_main_dir(
    const int* __restrict__ adj, const unsigned short* __restrict__ hpt,
    const float* __restrict__ s1g, const float* __restrict__ s2g,
    const float* __restrict__ s2max, float* __restrict__ out)
{
  __shared__ float red[8][64][17];
  __shared__ float lden[8][16];
  const int t = threadIdx.x;
  const int lane = t & 63;
  const int w = t >> 6;
  const int rb = blockIdx.x;
  const int r15 = lane & 15;
  const int kq = lane >> 4;
  const int row = rb * 16 + r15;

  const float s1v = s1g[row];
  const float SM = *s2max;
  const float xm = s1v + SM;
  const float msc = fmaxf(xm, ALPHA * xm) * LOG2E;

  const int kbase = w * 1024 + kq * 8;
  const int* aP = adj + (size_t)row * NN + kbase;
  const float* sP = s2g + kbase;
  const unsigned short* bP = hpt + (size_t)r15 * NN + w * 1024 + kq * 8;

  f32x4 acc0 = {0.f,0.f,0.f,0.f}, acc1 = acc0, acc2 = acc0, acc3 = acc0;
  float lpart = 0.f;

  int4  a0 = *reinterpret_cast<const int4*>(aP);
  int4  a1 = *reinterpret_cast<const int4*>(aP + 4);
  float4 sA = *reinterpret_cast<const float4*>(sP);
  float4 sB = *reinterpret_cast<const float4*>(sP + 4);
  short8 b0 = *reinterpret_cast<const short8*>(bP);
  short8 b1 = *reinterpret_cast<const short8*>(bP + 16 * NN);
  short8 b2 = *reinterpret_cast<const short8*>(bP + 32 * NN);
  short8 b3 = *reinterpret_cast<const short8*>(bP + 48 * NN);

  for (int st = 0; st < 32; ++st) {
    const int nk = (st < 31) ? (st + 1) * 32 : 0;
    const int4  na0 = *reinterpret_cast<const int4*>(aP + nk);
    const int4  na1 = *reinterpret_cast<const int4*>(aP + nk + 4);
    const float4 nsA = *reinterpret_cast<const float4*>(sP + nk);
    const float4 nsB = *reinterpret_cast<const float4*>(sP + nk + 4);
    const short8 nb0 = *reinterpret_cast<const short8*>(bP + nk);
    const short8 nb1 = *reinterpret_cast<const short8*>(bP + nk + 16 * NN);
    const short8 nb2 = *reinterpret_cast<const short8*>(bP + nk + 32 * NN);
    const short8 nb3 = *reinterpret_cast<const short8*>(bP + nk + 48 * NN);

    const ushort4 lo = p4i(a0, sA, s1v, msc, lpart);
    const ushort4 hi = p4i(a1, sB, s1v, msc, lpart);
    short8 af;
    af[0] = (short)lo.x; af[1] = (short)lo.y; af[2] = (short)lo.z; af[3] = (short)lo.w;
    af[4] = (short)hi.x; af[5] = (short)hi.y; af[6] = (short)hi.z; af[7] = (short)hi.w;
    acc0 = __builtin_amdgcn_mfma_f32_16x16x32_bf16(af, b0, acc0, 0, 0, 0);
    acc1 = __builtin_amdgcn_mfma_f32_16x16x32_bf16(af, b1, acc1, 0, 0, 0);
    acc2 = __builtin_amdgcn_mfma_f32_16x16x32_bf16(af, b2, acc2, 0, 0, 0);
    acc3 = __builtin_amdgcn_mfma_f32_16x16x32_bf16(af, b3, acc3, 0, 0, 0);

    a0 = na0; a1 = na1; sA = nsA; sB = nsB;
    b0 = nb0; b1 = nb1; b2 = nb2; b3 = nb3;
  }

  lpart += __shfl_xor(lpart, 16, 64);
  lpart += __shfl_xor(lpart, 32, 64);
  if (kq == 0) lden[w][r15] = lpart;

  #pragma unroll
  for (int r = 0; r < 4; ++r) {
    red[w][lane][r]      = acc0[r];
    red[w][lane][4 + r]  = acc1[r];
    red[w][lane][8 + r]  = acc2[r];
    red[w][lane][12 + r] = acc3[r];
  }
  __syncthreads();

  const int orow = t >> 5;
  const int oc = t & 31;
  float den = 0.f;
  #pragma unroll
  for (int ww = 0; ww < 8; ++ww) den += lden[ww][orow];
  const float inv = 1.f / den;
  #pragma unroll
  for (int half = 0; half < 2; ++half) {
    const int col = oc + 32 * half;
    const int s = col >> 4, c = col & 15;
    const int li = (orow >> 2) * 16 + c;
    const int ri = s * 4 + (orow & 3);
    float v = 0.f;
    #pragma unroll
    for (int ww = 0; ww < 8; ++ww) v += red[ww][li][ri];
    const float dv = v * inv;
    out[(size_t)(rb * 16 + orow) * OUTF + col] = dv > 0.f ? dv : (expf(dv) - 1.f);
  }
}

extern "C" void kernel_launch(void* const* d_in, const int* in_sizes, int n_in,
                              void* d_out, int out_size, void* d_ws, size_t ws_size,
                              hipStream_t stream) {
  (void)in_sizes; (void)n_in; (void)out_size;
  const float* X  = (const float*)d_in[0];
  const int* adj  = (const int*)d_in[1];
  const float* W  = (const float*)d_in[2];
  const float* a1 = (const float*)d_in[3];
  const float* a2 = (const float*)d_in[4];
  float* out = (float*)d_out;

  char* ws = (char*)d_ws;
  const size_t MASK_BYTES = (size_t)NN * NN / 8;   // 8 MB

  if (ws_size >= MASK_BYTES + 2 * 1024 * 1024) {
    unsigned long long* mask64 = (unsigned long long*)ws;
    unsigned short* hpt = (unsigned short*)(ws + MASK_BYTES);        // 1 MB
    float* s1   = (float*)(ws + MASK_BYTES + (size_t)OUTF * NN * 2);
    float* s2   = s1 + NN;
    float* pmax = s2 + NN;

    hipLaunchKernelGGL(k_pack, dim3(NN * NN / 2048 / 4), dim3(256), 0, stream, adj, mask64);
    hipLaunchKernelGGL(k_prep, dim3(256), dim3(256), 0, stream, X, W, a1, a2, hpt, s1, s2, pmax);
    hipLaunchKernelGGL(k_main_mask, dim3(512), dim3(512), 0, stream,
                       (const unsigned int*)mask64, hpt, s1, s2, pmax, out);
  } else {
    unsigned short* hpt = (unsigned short*)ws;
    float* s1   = (float*)(ws + (size_t)OUTF * NN * 2);
    float* s2   = s1 + NN;
    float* pmax = s2 + NN;
    float* s2m  = pmax + 256;

    hipLaunchKernelGGL(k_prep, dim3(256), dim3(256), 0, stream, X, W, a1, a2, hpt, s1, s2, pmax);
    hipLaunchKernelGGL(k_rmax, dim3(1), dim3(64), 0, stream, pmax, s2m);
    hipLaunchKernelGGL(k_main_dir, dim3(512), dim3(512), 0, stream, adj, hpt, s1, s2, s2m, out);
  }
}

// Round 4
// 121.742 us; speedup vs baseline: 1.1189x; 1.1189x over previous
//
#include <hip/hip_runtime.h>
#include <hip/hip_bf16.h>

#define NN 8192
#define INF_ 256
#define OUTF 64
#define ALPHA 0.2f

typedef __attribute__((ext_vector_type(8))) short short8;
typedef __attribute__((ext_vector_type(4))) float f32x4;

static __device__ __forceinline__ unsigned short f2bf(float f) {
  unsigned u = __builtin_bit_cast(unsigned, f);
  u += 0x7fffu + ((u >> 16) & 1u);          // RNE; inputs are finite
  return (unsigned short)(u >> 16);
}

// ---------------- Kernel P: adj int32 -> tiled bitmask.
// Output word for (rt, tgg, kq, r15): byte i (i=0..3), bit j = adj[rt*16+r15][(4*tgg+i)*32 + kq*8 + j] > 0.
// Word index = ((rt*64 + tgg)*64 + kq*16 + r15). One thread builds one word (reads 32 ints).
__global__ __launch_bounds__(256) void k_pack(const int* __restrict__ adj,
                                              unsigned int* __restrict__ maskT) {
  const int g = blockIdx.x * 256 + threadIdx.x;   // 2M threads
  const int row = g >> 8;
  const int rem = g & 255;
  const int kq = rem >> 6;
  const int tgg = rem & 63;
  const int* ap = adj + (size_t)row * NN + tgg * 128 + kq * 8;
  unsigned wd = 0;
  #pragma unroll
  for (int i = 0; i < 4; ++i) {
    const int4 c0 = *reinterpret_cast<const int4*>(ap + i * 32);
    const int4 c1 = *reinterpret_cast<const int4*>(ap + i * 32 + 4);
    unsigned by = (unsigned)(c0.x > 0)       | ((unsigned)(c0.y > 0) << 1)
                | ((unsigned)(c0.z > 0) << 2) | ((unsigned)(c0.w > 0) << 3)
                | ((unsigned)(c1.x > 0) << 4) | ((unsigned)(c1.y > 0) << 5)
                | ((unsigned)(c1.z > 0) << 6) | ((unsigned)(c1.w > 0) << 7);
    wd |= by << (8 * i);
  }
  maskT[(((size_t)(row >> 4) * 64 + tgg) * 64) + kq * 16 + (row & 15)] = wd;
}

// ---------------- Kernel A: h' = X@W -> hptF (bf16, MFMA B-fragment order), s1, s2, block s2max
// hptF[((t*4+s)*64 + lane)*8 + j] = h'[t*32 + (lane>>4)*8 + j][s*16 + (lane&15)]
__global__ __launch_bounds__(256) void k_prep(
    const float* __restrict__ X, const float* __restrict__ W,
    const float* __restrict__ a1, const float* __restrict__ a2,
    unsigned short* __restrict__ hptF, float* __restrict__ s1,
    float* __restrict__ s2, float* __restrict__ pmax)
{
  __shared__ float Ws[INF_ * OUTF];   // 64 KB
  __shared__ float Xs[32 * INF_];     // 32 KB
  __shared__ float sm8[8];
  const int t = threadIdx.x;
  const int ib = blockIdx.x;

  #pragma unroll
  for (int i = 0; i < 16; ++i) {
    const int idx = (i * 256 + t) * 4;
    *reinterpret_cast<float4*>(&Ws[idx]) = *reinterpret_cast<const float4*>(&W[idx]);
  }
  const float* Xb = X + (size_t)ib * 32 * INF_;
  #pragma unroll
  for (int i = 0; i < 8; ++i) {
    const int idx = (i * 256 + t) * 4;
    *reinterpret_cast<float4*>(&Xs[idx]) = *reinterpret_cast<const float4*>(&Xb[idx]);
  }
  __syncthreads();

  const int rg = t >> 5;          // 0..7 -> nodes 4*rg..4*rg+3
  const int r0 = rg * 4;
  const int c0 = 2 * (t & 31);    // 2 consecutive output features
  float acc[4][2] = {{0.f,0.f},{0.f,0.f},{0.f,0.f},{0.f,0.f}};

  for (int k = 0; k < INF_; k += 4) {
    float xv[4][4];
    #pragma unroll
    for (int rr = 0; rr < 4; ++rr)
      *reinterpret_cast<float4*>(&xv[rr][0]) =
          *reinterpret_cast<const float4*>(&Xs[(r0 + rr) * INF_ + k]);
    #pragma unroll
    for (int kk = 0; kk < 4; ++kk) {
      const float2 wv = *reinterpret_cast<const float2*>(&Ws[(k + kk) * OUTF + c0]);
      #pragma unroll
      for (int rr = 0; rr < 4; ++rr) {
        acc[rr][0] = fmaf(xv[rr][kk], wv.x, acc[rr][0]);
        acc[rr][1] = fmaf(xv[rr][kk], wv.y, acc[rr][1]);
      }
    }
  }

  const float a10 = a1[c0], a11 = a1[c0 + 1];
  const float a20 = a2[c0], a21 = a2[c0 + 1];
  float sp1[4], sp2[4];
  #pragma unroll
  for (int rr = 0; rr < 4; ++rr) {
    sp1[rr] = acc[rr][0] * a10 + acc[rr][1] * a11;
    sp2[rr] = acc[rr][0] * a20 + acc[rr][1] * a21;
  }
  #pragma unroll
  for (int d = 1; d < 32; d <<= 1) {
    #pragma unroll
    for (int rr = 0; rr < 4; ++rr) {
      sp1[rr] += __shfl_xor(sp1[rr], d, 64);
      sp2[rr] += __shfl_xor(sp2[rr], d, 64);
    }
  }

  // fragment-order store: 4 consecutive nodes = consecutive j within one (t=ib, s, lane) slot
  const int jj0 = (rg & 1) * 4;
  const int lhi = rg >> 1;
  #pragma unroll
  for (int cc = 0; cc < 2; ++cc) {
    const int feat = c0 + cc;
    const int s = feat >> 4;
    const int ln = lhi * 16 + (feat & 15);
    ushort4 pk;
    pk.x = f2bf(acc[0][cc]); pk.y = f2bf(acc[1][cc]);
    pk.z = f2bf(acc[2][cc]); pk.w = f2bf(acc[3][cc]);
    *reinterpret_cast<ushort4*>(&hptF[(size_t)ib * 2048 + s * 512 + ln * 8 + jj0]) = pk;
  }
  const int gr = ib * 32 + r0;
  if ((t & 31) == 0) {
    #pragma unroll
    for (int rr = 0; rr < 4; ++rr) { s1[gr + rr] = sp1[rr]; s2[gr + rr] = sp2[rr]; }
    sm8[rg] = fmaxf(fmaxf(sp2[0], sp2[1]), fmaxf(sp2[2], sp2[3]));
  }
  __syncthreads();
  if (t == 0) {
    float m = sm8[0];
    #pragma unroll
    for (int i = 1; i < 8; ++i) m = fmaxf(m, sm8[i]);
    pmax[ib] = m;
  }
}

// ---------------- Kernel R: global max of s2
__global__ void k_rmax(const float* __restrict__ pmax, float* __restrict__ s2max) {
  const int t = threadIdx.x;  // 64 threads
  float m = fmaxf(fmaxf(pmax[t], pmax[t + 64]), fmaxf(pmax[t + 128], pmax[t + 192]));
  #pragma unroll
  for (int d = 1; d < 64; d <<= 1) m = fmaxf(m, __shfl_xor(m, d, 64));
  if (t == 0) *s2max = m;
}

// ---------------- Kernel E: factor tables.
// exp(lrelu(s1_i+s2_j) - m_i) == (E2_j >= TR_i) ? E1_i*E2_j : F1_i*F2_j, all factors in [0,1]-ish.
__global__ __launch_bounds__(256) void k_ef(
    const float* __restrict__ s1, const float* __restrict__ s2,
    const float* __restrict__ s2m, float* __restrict__ ef2, float4* __restrict__ rowp)
{
  const int i = blockIdx.x * 256 + threadIdx.x;   // 8192
  const float S2M = *s2m;
  const float d = s2[i] - S2M;
  ef2[2 * i]     = expf(d);            // E2
  ef2[2 * i + 1] = expf(ALPHA * d);    // F2
  const float y = s1[i] + S2M;         // m_i = lrelu(y)
  const float e1 = y >= 0.f ? 1.f : expf((1.f - ALPHA) * y);
  const float f1 = y >= 0.f ? expf(-(1.f - ALPHA) * y) : 1.f;
  const float tr = expf(-y);           // cond: E2 >= TR  <=>  s1+s2 >= 0
  rowp[i] = make_float4(e1, f1, tr, 0.f);
}

// ---------------- Kernel C: fused masked-softmax + attn@h' + elu.
// 512 blocks x 512 thr; block = 16 output rows; 8 waves split K (1024 each = 32 k-steps).
// Coalesced fragment loads; no in-loop transcendentals; denominator via ones-column MFMA.
__global__ __launch_bounds__(512, 4) void k_main(
    const unsigned int* __restrict__ maskT, const unsigned short* __restrict__ hptF,
    const float* __restrict__ ef2, const float4* __restrict__ rowp,
    float* __restrict__ out)
{
  __shared__ float red[8][64][17];   // +1 pad: conflict-free
  __shared__ float lden[8][16];
  const int t = threadIdx.x;
  const int lane = t & 63;
  const int w = t >> 6;            // K-chunk 0..7
  const int rt = blockIdx.x;       // row tile (16 rows)
  const int r15 = lane & 15;

  const float4 rp = rowp[rt * 16 + r15];
  const float E1 = rp.x, F1 = rp.y, TR = rp.z;

  short8 bones;                    // B ones-column fragment: B[k][0]=1
  {
    const short v = (r15 == 0) ? (short)0x3F80 : (short)0;
    bones[0]=v; bones[1]=v; bones[2]=v; bones[3]=v;
    bones[4]=v; bones[5]=v; bones[6]=v; bones[7]=v;
  }

  f32x4 acc0 = {0.f,0.f,0.f,0.f}, acc1 = acc0, acc2 = acc0, acc3 = acc0, acc4 = acc0;
  const unsigned int* mT = maskT + ((size_t)rt * 64 + w * 8) * 64 + lane;

  for (int tg = 0; tg < 8; ++tg) {
    const unsigned mw = mT[tg * 64];
    #pragma unroll
    for (int i = 0; i < 4; ++i) {
      const int tglob = w * 32 + tg * 4 + i;
      const unsigned short* bp = hptF + (size_t)tglob * 2048 + lane * 8;
      const short8 b0 = *reinterpret_cast<const short8*>(bp);
      const short8 b1 = *reinterpret_cast<const short8*>(bp + 512);
      const short8 b2 = *reinterpret_cast<const short8*>(bp + 1024);
      const short8 b3 = *reinterpret_cast<const short8*>(bp + 1536);
      const float* ep = ef2 + (size_t)tglob * 64 + (lane >> 4) * 16;
      const float4 eA = *reinterpret_cast<const float4*>(ep);       // E2,F2 pairs
      const float4 eB = *reinterpret_cast<const float4*>(ep + 4);
      const float4 eC = *reinterpret_cast<const float4*>(ep + 8);
      const float4 eD = *reinterpret_cast<const float4*>(ep + 12);
      const unsigned mb = (mw >> (8 * i)) & 0xFFu;

      const float p0 = (mb & 1u)   ? ((eA.x >= TR) ? E1 * eA.x : F1 * eA.y) : 0.f;
      const float p1 = (mb & 2u)   ? ((eA.z >= TR) ? E1 * eA.z : F1 * eA.w) : 0.f;
      const float p2 = (mb & 4u)   ? ((eB.x >= TR) ? E1 * eB.x : F1 * eB.y) : 0.f;
      const float p3 = (mb & 8u)   ? ((eB.z >= TR) ? E1 * eB.z : F1 * eB.w) : 0.f;
      const float p4 = (mb & 16u)  ? ((eC.x >= TR) ? E1 * eC.x : F1 * eC.y) : 0.f;
      const float p5 = (mb & 32u)  ? ((eC.z >= TR) ? E1 * eC.z : F1 * eC.w) : 0.f;
      const float p6 = (mb & 64u)  ? ((eD.x >= TR) ? E1 * eD.x : F1 * eD.y) : 0.f;
      const float p7 = (mb & 128u) ? ((eD.z >= TR) ? E1 * eD.z : F1 * eD.w) : 0.f;

      unsigned q0, q1, q2, q3;
      asm("v_cvt_pk_bf16_f32 %0, %1, %2" : "=v"(q0) : "v"(p0), "v"(p1));
      asm("v_cvt_pk_bf16_f32 %0, %1, %2" : "=v"(q1) : "v"(p2), "v"(p3));
      asm("v_cvt_pk_bf16_f32 %0, %1, %2" : "=v"(q2) : "v"(p4), "v"(p5));
      asm("v_cvt_pk_bf16_f32 %0, %1, %2" : "=v"(q3) : "v"(p6), "v"(p7));
      union { unsigned u[4]; short8 s8; } cv;
      cv.u[0] = q0; cv.u[1] = q1; cv.u[2] = q2; cv.u[3] = q3;
      const short8 af = cv.s8;

      acc0 = __builtin_amdgcn_mfma_f32_16x16x32_bf16(af, b0, acc0, 0, 0, 0);
      acc1 = __builtin_amdgcn_mfma_f32_16x16x32_bf16(af, b1, acc1, 0, 0, 0);
      acc2 = __builtin_amdgcn_mfma_f32_16x16x32_bf16(af, b2, acc2, 0, 0, 0);
      acc3 = __builtin_amdgcn_mfma_f32_16x16x32_bf16(af, b3, acc3, 0, 0, 0);
      acc4 = __builtin_amdgcn_mfma_f32_16x16x32_bf16(af, bones, acc4, 0, 0, 0);
    }
  }

  // denominator partials: acc4 col 0 lives at lanes with r15==0; rows (lane>>4)*4+r
  if (r15 == 0) {
    #pragma unroll
    for (int r = 0; r < 4; ++r) lden[w][(lane >> 4) * 4 + r] = acc4[r];
  }
  #pragma unroll
  for (int r = 0; r < 4; ++r) {
    red[w][lane][r]      = acc0[r];
    red[w][lane][4 + r]  = acc1[r];
    red[w][lane][8 + r]  = acc2[r];
    red[w][lane][12 + r] = acc3[r];
  }
  __syncthreads();

  // 1024 outputs / 512 threads = 2 each. C/D layout: col=s*16+(lane&15), row=(lane>>4)*4+reg
  const int orow = t >> 5;     // 0..15
  const int oc = t & 31;       // cols oc and oc+32
  float den = 0.f;
  #pragma unroll
  for (int ww = 0; ww < 8; ++ww) den += lden[ww][orow];
  const float inv = 1.f / den;
  #pragma unroll
  for (int half = 0; half < 2; ++half) {
    const int col = oc + 32 * half;
    const int s = col >> 4, c = col & 15;
    const int li = (orow >> 2) * 16 + c;
    const int ri = s * 4 + (orow & 3);
    float v = 0.f;
    #pragma unroll
    for (int ww = 0; ww < 8; ++ww) v += red[ww][li][ri];
    const float dv = v * inv;
    out[(size_t)(rt * 16 + orow) * OUTF + col] = dv > 0.f ? dv : (expf(dv) - 1.f);
  }
}

extern "C" void kernel_launch(void* const* d_in, const int* in_sizes, int n_in,
                              void* d_out, int out_size, void* d_ws, size_t ws_size,
                              hipStream_t stream) {
  (void)in_sizes; (void)n_in; (void)out_size; (void)ws_size;
  const float* X  = (const float*)d_in[0];
  const int* adj  = (const int*)d_in[1];
  const float* W  = (const float*)d_in[2];
  const float* a1 = (const float*)d_in[3];
  const float* a2 = (const float*)d_in[4];
  float* out = (float*)d_out;

  char* ws = (char*)d_ws;
  const size_t MASK_BYTES = (size_t)NN * NN / 8;                 // 8 MB
  unsigned int* maskT = (unsigned int*)ws;
  unsigned short* hptF = (unsigned short*)(ws + MASK_BYTES);     // 1 MB
  char* p2 = ws + MASK_BYTES + (size_t)OUTF * NN * 2;
  float* s1   = (float*)p2;                                      // 32 KB
  float* s2   = s1 + NN;                                         // 32 KB
  float* pmax = s2 + NN;                                         // 1 KB
  float* s2m  = pmax + 256;                                      // pad to 64 floats
  float* ef2  = s2m + 64;                                        // 64 KB
  float4* rowp = (float4*)(ef2 + 2 * NN);                        // 128 KB

  hipLaunchKernelGGL(k_pack, dim3(NN * 256 / 256), dim3(256), 0, stream, adj, maskT);
  hipLaunchKernelGGL(k_prep, dim3(256), dim3(256), 0, stream, X, W, a1, a2, hptF, s1, s2, pmax);
  hipLaunchKernelGGL(k_rmax, dim3(1), dim3(64), 0, stream, pmax, s2m);
  hipLaunchKernelGGL(k_ef, dim3(NN / 256), dim3(256), 0, stream, s1, s2, s2m, ef2, rowp);
  hipLaunchKernelGGL(k_main, dim3(512), dim3(512), 0, stream, maskT, hptF, ef2, rowp, out);
}

// Round 5
// 93.307 us; speedup vs baseline: 1.4599x; 1.3048x over previous
//
#include <hip/hip_runtime.h>
#include <hip/hip_bf16.h>

#define NN 8192
#define INF_ 256
#define OUTF 64
#define ALPHA 0.2f

typedef __attribute__((ext_vector_type(8))) short short8;
typedef __attribute__((ext_vector_type(4))) float f32x4;

static __device__ __forceinline__ unsigned short f2bf(float f) {
  unsigned u = __builtin_bit_cast(unsigned, f);
  u += 0x7fffu + ((u >> 16) & 1u);          // RNE; inputs are finite
  return (unsigned short)(u >> 16);
}

// ---------------- Kernel A: h' = X@W -> hptF (bf16, MFMA B-fragment order), s1, s2, block s2max
// hptF[((t*4+s)*64 + lane)*8 + j] = h'[t*32 + (lane>>4)*8 + j][s*16 + (lane&15)]
__global__ __launch_bounds__(256) void k_prep(
    const float* __restrict__ X, const float* __restrict__ W,
    const float* __restrict__ a1, const float* __restrict__ a2,
    unsigned short* __restrict__ hptF, float* __restrict__ s1,
    float* __restrict__ s2, float* __restrict__ pmax)
{
  __shared__ float Ws[INF_ * OUTF];   // 64 KB
  __shared__ float Xs[32 * INF_];     // 32 KB
  __shared__ float sm8[8];
  const int t = threadIdx.x;
  const int ib = blockIdx.x;

  #pragma unroll
  for (int i = 0; i < 16; ++i) {
    const int idx = (i * 256 + t) * 4;
    *reinterpret_cast<float4*>(&Ws[idx]) = *reinterpret_cast<const float4*>(&W[idx]);
  }
  const float* Xb = X + (size_t)ib * 32 * INF_;
  #pragma unroll
  for (int i = 0; i < 8; ++i) {
    const int idx = (i * 256 + t) * 4;
    *reinterpret_cast<float4*>(&Xs[idx]) = *reinterpret_cast<const float4*>(&Xb[idx]);
  }
  __syncthreads();

  const int rg = t >> 5;          // 0..7 -> nodes 4*rg..4*rg+3
  const int r0 = rg * 4;
  const int c0 = 2 * (t & 31);    // 2 consecutive output features
  float acc[4][2] = {{0.f,0.f},{0.f,0.f},{0.f,0.f},{0.f,0.f}};

  for (int k = 0; k < INF_; k += 4) {
    float xv[4][4];
    #pragma unroll
    for (int rr = 0; rr < 4; ++rr)
      *reinterpret_cast<float4*>(&xv[rr][0]) =
          *reinterpret_cast<const float4*>(&Xs[(r0 + rr) * INF_ + k]);
    #pragma unroll
    for (int kk = 0; kk < 4; ++kk) {
      const float2 wv = *reinterpret_cast<const float2*>(&Ws[(k + kk) * OUTF + c0]);
      #pragma unroll
      for (int rr = 0; rr < 4; ++rr) {
        acc[rr][0] = fmaf(xv[rr][kk], wv.x, acc[rr][0]);
        acc[rr][1] = fmaf(xv[rr][kk], wv.y, acc[rr][1]);
      }
    }
  }

  const float a10 = a1[c0], a11 = a1[c0 + 1];
  const float a20 = a2[c0], a21 = a2[c0 + 1];
  float sp1[4], sp2[4];
  #pragma unroll
  for (int rr = 0; rr < 4; ++rr) {
    sp1[rr] = acc[rr][0] * a10 + acc[rr][1] * a11;
    sp2[rr] = acc[rr][0] * a20 + acc[rr][1] * a21;
  }
  #pragma unroll
  for (int d = 1; d < 32; d <<= 1) {
    #pragma unroll
    for (int rr = 0; rr < 4; ++rr) {
      sp1[rr] += __shfl_xor(sp1[rr], d, 64);
      sp2[rr] += __shfl_xor(sp2[rr], d, 64);
    }
  }

  // fragment-order store: 4 consecutive nodes = consecutive j within one (t=ib, s, lane) slot
  const int jj0 = (rg & 1) * 4;
  const int lhi = rg >> 1;
  #pragma unroll
  for (int cc = 0; cc < 2; ++cc) {
    const int feat = c0 + cc;
    const int s = feat >> 4;
    const int ln = lhi * 16 + (feat & 15);
    ushort4 pk;
    pk.x = f2bf(acc[0][cc]); pk.y = f2bf(acc[1][cc]);
    pk.z = f2bf(acc[2][cc]); pk.w = f2bf(acc[3][cc]);
    *reinterpret_cast<ushort4*>(&hptF[(size_t)ib * 2048 + s * 512 + ln * 8 + jj0]) = pk;
  }
  const int gr = ib * 32 + r0;
  if ((t & 31) == 0) {
    #pragma unroll
    for (int rr = 0; rr < 4; ++rr) { s1[gr + rr] = sp1[rr]; s2[gr + rr] = sp2[rr]; }
    sm8[rg] = fmaxf(fmaxf(sp2[0], sp2[1]), fmaxf(sp2[2], sp2[3]));
  }
  __syncthreads();
  if (t == 0) {
    float m = sm8[0];
    #pragma unroll
    for (int i = 1; i < 8; ++i) m = fmaxf(m, sm8[i]);
    pmax[ib] = m;
  }
}

// ---------------- Kernel E: global s2-max (internal reduction of pmax[256]) + factor tables.
// exp(lrelu(s1_i+s2_j) - m_i) == (s1_i+s2_j>=0 i.e. E2_j>=TR_i) ? E1_i*E2_j : F1_i*F2_j.
__global__ __launch_bounds__(256) void k_ef(
    const float* __restrict__ s1, const float* __restrict__ s2,
    const float* __restrict__ pmax, float* __restrict__ ef2, float4* __restrict__ rowp)
{
  __shared__ float smx[4];
  const int t = threadIdx.x;
  float m = pmax[t];                       // 256 threads, 256 entries
  #pragma unroll
  for (int d = 1; d < 64; d <<= 1) m = fmaxf(m, __shfl_xor(m, d, 64));
  if ((t & 63) == 0) smx[t >> 6] = m;
  __syncthreads();
  const float S2M = fmaxf(fmaxf(smx[0], smx[1]), fmaxf(smx[2], smx[3]));

  const int i = blockIdx.x * 256 + t;      // 8192
  const float d = s2[i] - S2M;
  ef2[2 * i]     = expf(d);                // E2 <= 1
  ef2[2 * i + 1] = expf(ALPHA * d);        // F2 <= 1
  const float y = s1[i] + S2M;             // m_i = lrelu(y)
  const float e1 = y >= 0.f ? 1.f : expf((1.f - ALPHA) * y);
  const float f1 = y >= 0.f ? expf(-(1.f - ALPHA) * y) : 1.f;
  const float tr = expf(-y);               // E2_j >= TR_i  <=>  s1_i+s2_j >= 0
  rowp[i] = make_float4(e1, f1, tr, 0.f);
}

// ---------------- Kernel C: fused masked-softmax + attn@h' + elu, streaming adj directly.
// 512 blocks x 512 thr; block = 16 output rows; 8 waves split K (1024 cols each = 32 k-steps).
// Per k-step a lane reads 8 adj ints (rows at 32KB stride -> 16 full lines/instr per wave),
// builds its MFMA A-fragment in registers via the factor tables (no transcendentals),
// prefetches 2 k-steps ahead. Memory-bound on the 256MB adj stream.
__global__ __launch_bounds__(512, 4) void k_main(
    const int* __restrict__ adj, const unsigned short* __restrict__ hptF,
    const float* __restrict__ ef2, const float4* __restrict__ rowp,
    float* __restrict__ out)
{
  __shared__ float red[8][64][17];   // +1 pad: conflict-free
  __shared__ float lden[8][16];
  const int t = threadIdx.x;
  const int lane = t & 63;
  const int w = t >> 6;            // K-chunk 0..7
  const int rt = blockIdx.x;       // row tile (16 rows)
  const int r15 = lane & 15;
  const int kq = lane >> 4;        // k-quad: cols kq*8..kq*8+7 within each 32-col k-step
  const int row = rt * 16 + r15;

  const float4 rp = rowp[row];
  const float E1 = rp.x, F1 = rp.y, TR = rp.z;

  const int* aP = adj + (size_t)row * NN + w * 1024 + kq * 8;

  f32x4 acc0 = {0.f,0.f,0.f,0.f}, acc1 = acc0, acc2 = acc0, acc3 = acc0;
  float lpart = 0.f;

  // prefetch k-steps 0,1 (2 int4 each)
  int4 c[4];
  c[0] = *reinterpret_cast<const int4*>(aP);
  c[1] = *reinterpret_cast<const int4*>(aP + 4);
  c[2] = *reinterpret_cast<const int4*>(aP + 32);
  c[3] = *reinterpret_cast<const int4*>(aP + 36);

  for (int tg = 0; tg < 16; ++tg) {         // 2 k-steps per iter
    const int* np = aP + ((tg < 15) ? (tg + 1) * 64 : 0);   // tail reloads (discarded)
    int4 n[4];
    n[0] = *reinterpret_cast<const int4*>(np);
    n[1] = *reinterpret_cast<const int4*>(np + 4);
    n[2] = *reinterpret_cast<const int4*>(np + 32);
    n[3] = *reinterpret_cast<const int4*>(np + 36);

    #pragma unroll
    for (int i = 0; i < 2; ++i) {
      const int tglob = (w << 5) + (tg << 1) + i;
      const unsigned short* bp = hptF + ((size_t)tglob << 11) + (lane << 3);
      const short8 b0 = *reinterpret_cast<const short8*>(bp);
      const short8 b1 = *reinterpret_cast<const short8*>(bp + 512);
      const short8 b2 = *reinterpret_cast<const short8*>(bp + 1024);
      const short8 b3 = *reinterpret_cast<const short8*>(bp + 1536);
      const float* ep = ef2 + (tglob << 6) + (kq << 4);
      const float4 eA = *reinterpret_cast<const float4*>(ep);       // {E2,F2} pairs
      const float4 eB = *reinterpret_cast<const float4*>(ep + 4);
      const float4 eC = *reinterpret_cast<const float4*>(ep + 8);
      const float4 eD = *reinterpret_cast<const float4*>(ep + 12);
      const int4 A  = c[2 * i];
      const int4 B4 = c[2 * i + 1];

      const float p0 = (A.x  > 0) ? ((eA.x >= TR) ? E1 * eA.x : F1 * eA.y) : 0.f;
      const float p1 = (A.y  > 0) ? ((eA.z >= TR) ? E1 * eA.z : F1 * eA.w) : 0.f;
      const float p2 = (A.z  > 0) ? ((eB.x >= TR) ? E1 * eB.x : F1 * eB.y) : 0.f;
      const float p3 = (A.w  > 0) ? ((eB.z >= TR) ? E1 * eB.z : F1 * eB.w) : 0.f;
      const float p4 = (B4.x > 0) ? ((eC.x >= TR) ? E1 * eC.x : F1 * eC.y) : 0.f;
      const float p5 = (B4.y > 0) ? ((eC.z >= TR) ? E1 * eC.z : F1 * eC.w) : 0.f;
      const float p6 = (B4.z > 0) ? ((eD.x >= TR) ? E1 * eD.x : F1 * eD.y) : 0.f;
      const float p7 = (B4.w > 0) ? ((eD.z >= TR) ? E1 * eD.z : F1 * eD.w) : 0.f;
      lpart += ((p0 + p1) + (p2 + p3)) + ((p4 + p5) + (p6 + p7));

      unsigned q0, q1, q2, q3;
      asm("v_cvt_pk_bf16_f32 %0, %1, %2" : "=v"(q0) : "v"(p0), "v"(p1));
      asm("v_cvt_pk_bf16_f32 %0, %1, %2" : "=v"(q1) : "v"(p2), "v"(p3));
      asm("v_cvt_pk_bf16_f32 %0, %1, %2" : "=v"(q2) : "v"(p4), "v"(p5));
      asm("v_cvt_pk_bf16_f32 %0, %1, %2" : "=v"(q3) : "v"(p6), "v"(p7));
      union { unsigned u[4]; short8 s8; } cv;
      cv.u[0] = q0; cv.u[1] = q1; cv.u[2] = q2; cv.u[3] = q3;
      const short8 af = cv.s8;

      acc0 = __builtin_amdgcn_mfma_f32_16x16x32_bf16(af, b0, acc0, 0, 0, 0);
      acc1 = __builtin_amdgcn_mfma_f32_16x16x32_bf16(af, b1, acc1, 0, 0, 0);
      acc2 = __builtin_amdgcn_mfma_f32_16x16x32_bf16(af, b2, acc2, 0, 0, 0);
      acc3 = __builtin_amdgcn_mfma_f32_16x16x32_bf16(af, b3, acc3, 0, 0, 0);
    }
    #pragma unroll
    for (int j = 0; j < 4; ++j) c[j] = n[j];
  }

  // denominator partials: sum the 4 k-quads of each row
  lpart += __shfl_xor(lpart, 16, 64);
  lpart += __shfl_xor(lpart, 32, 64);
  if (kq == 0) lden[w][r15] = lpart;

  #pragma unroll
  for (int r = 0; r < 4; ++r) {
    red[w][lane][r]      = acc0[r];
    red[w][lane][4 + r]  = acc1[r];
    red[w][lane][8 + r]  = acc2[r];
    red[w][lane][12 + r] = acc3[r];
  }
  __syncthreads();

  // 1024 outputs / 512 threads = 2 each. C/D layout: col=s*16+(lane&15), row=(lane>>4)*4+reg
  const int orow = t >> 5;     // 0..15
  const int oc = t & 31;       // cols oc and oc+32
  float den = 0.f;
  #pragma unroll
  for (int ww = 0; ww < 8; ++ww) den += lden[ww][orow];
  const float inv = 1.f / den;
  #pragma unroll
  for (int half = 0; half < 2; ++half) {
    const int col = oc + 32 * half;
    const int s = col >> 4, cc = col & 15;
    const int li = (orow >> 2) * 16 + cc;
    const int ri = s * 4 + (orow & 3);
    float v = 0.f;
    #pragma unroll
    for (int ww = 0; ww < 8; ++ww) v += red[ww][li][ri];
    const float dv = v * inv;
    out[(size_t)(rt * 16 + orow) * OUTF + col] = dv > 0.f ? dv : (expf(dv) - 1.f);
  }
}

extern "C" void kernel_launch(void* const* d_in, const int* in_sizes, int n_in,
                              void* d_out, int out_size, void* d_ws, size_t ws_size,
                              hipStream_t stream) {
  (void)in_sizes; (void)n_in; (void)out_size; (void)ws_size;
  const float* X  = (const float*)d_in[0];
  const int* adj  = (const int*)d_in[1];
  const float* W  = (const float*)d_in[2];
  const float* a1 = (const float*)d_in[3];
  const float* a2 = (const float*)d_in[4];
  float* out = (float*)d_out;

  char* ws = (char*)d_ws;
  unsigned short* hptF = (unsigned short*)ws;                    // 1 MB
  float* s1   = (float*)(ws + (size_t)OUTF * NN * 2);            // 32 KB
  float* s2   = s1 + NN;                                         // 32 KB
  float* pmax = s2 + NN;                                         // 1 KB (pad to 256)
  float* ef2  = pmax + 256;                                      // 64 KB
  float4* rowp = (float4*)(ef2 + 2 * NN);                        // 128 KB

  hipLaunchKernelGGL(k_prep, dim3(256), dim3(256), 0, stream, X, W, a1, a2, hptF, s1, s2, pmax);
  hipLaunchKernelGGL(k_ef, dim3(NN / 256), dim3(256), 0, stream, s1, s2, pmax, ef2, rowp);
  hipLaunchKernelGGL(k_main, dim3(512), dim3(512), 0, stream, adj, hptF, ef2, rowp, out);
}